// Round 12
// baseline (410.965 us; speedup 1.0000x reference)
//
#include <hip/hip_runtime.h>
#include <hip/hip_bf16.h>

// SMoE: B=4 S=2048 D=1024 F=2048 E=8 K=2
#define DD 1024
#define FF 2048
#define EE 8
#define NT 8192            // B*S tokens
#define NRCAP 17280        // 135 tiles of 128 rows
#define MAXT128 135

typedef __attribute__((ext_vector_type(8))) short bf16x8;
typedef __attribute__((ext_vector_type(4))) float f32x4;

__device__ __forceinline__ ushort f2bf(float f) {
  __hip_bfloat16 h = __float2bfloat16(f);
  return *reinterpret_cast<ushort*>(&h);
}

__device__ __forceinline__ void gload16(const void* g, void* l) {
  __builtin_amdgcn_global_load_lds((const __attribute__((address_space(1))) void*)g,
                                   (__attribute__((address_space(3))) void*)l, 16, 0, 0);
}

// 4-slot XOR swizzle for [row][32 bf16] LDS tiles (verified R1-R11: ~0 bank conflicts)
__device__ __forceinline__ int swz_of_row(int r) { return ((r >> 1) & 3) << 4; }

// ---------------- front mega-kernel: rms_gate (bid<2048) + all weight transposes -------------
// bid in [0,2048): RMSNorm+gating for tokens 4*bid..+3 (1 wave/token, coalesced Wg, no atomics)
// bid in [2048,14336): transpose block tb=bid-2048: z=tb>>9 (0..23), rem=tb&511, bx=rem&31, by=rem>>5
//   z<16: W1a/W1b -> BT1 interleaved [E][4096][D];  z>=16: W2 -> W2T [E][D][F]
__global__ __launch_bounds__(256) void k_front(
    const float* __restrict__ x, const float* __restrict__ rms_w,
    const float* __restrict__ Wg, const float* __restrict__ bg,
    const float* __restrict__ W1a, const float* __restrict__ W1b, const float* __restrict__ W2,
    ushort* __restrict__ xn, float* __restrict__ outW,
    int* __restrict__ tk_e, float* __restrict__ tk_w,
    ushort* __restrict__ BT1, ushort* __restrict__ W2T) {
  __shared__ ushort tile[64][68];
  const int bid = blockIdx.x;
  if (bid < 2048) {
    const int t = bid * 4 + (threadIdx.x >> 6);
    const int lane = threadIdx.x & 63;
    const float* xrow = x + (size_t)t * DD;
    const float4* x4 = reinterpret_cast<const float4*>(xrow);
    const float4* w4 = reinterpret_cast<const float4*>(rms_w);
    const float4* Wg4 = reinterpret_cast<const float4*>(Wg);
    float4 xv[4];
    float ss = 0.f;
    #pragma unroll
    for (int i = 0; i < 4; i++) {
      xv[i] = x4[i * 64 + lane];
      ss += xv[i].x * xv[i].x + xv[i].y * xv[i].y + xv[i].z * xv[i].z + xv[i].w * xv[i].w;
    }
    #pragma unroll
    for (int m = 32; m; m >>= 1) ss += __shfl_xor(ss, m);
    const float sc = 1.0f / sqrtf(ss * (1.0f / (float)DD) + 1.1920929e-07f);  // finfo(f32).eps
    ushort4* xout = reinterpret_cast<ushort4*>(xn + (size_t)t * DD);
    #pragma unroll
    for (int i = 0; i < 4; i++) {
      const float4 wv = w4[i * 64 + lane];
      xout[i * 64 + lane] = make_ushort4(f2bf(xv[i].x * sc * wv.x), f2bf(xv[i].y * sc * wv.y),
                                         f2bf(xv[i].z * sc * wv.z), f2bf(xv[i].w * sc * wv.w));
    }
    // gating: lane l reads Wg4[l + 64k] (fully coalesced); expert-half (l&1) of row (l>>1)+32k
    float4 lgv = make_float4(0.f, 0.f, 0.f, 0.f);
    #pragma unroll 8
    for (int k = 0; k < 32; k++) {
      const int d = (lane >> 1) + 32 * k;
      const float s = xrow[d] * sc * rms_w[d];
      const float4 wg = Wg4[lane + 64 * k];
      lgv.x += s * wg.x; lgv.y += s * wg.y; lgv.z += s * wg.z; lgv.w += s * wg.w;
    }
    #pragma unroll
    for (int m = 32; m >= 2; m >>= 1) {
      lgv.x += __shfl_xor(lgv.x, m);
      lgv.y += __shfl_xor(lgv.y, m);
      lgv.z += __shfl_xor(lgv.z, m);
      lgv.w += __shfl_xor(lgv.w, m);
    }
    float4 other;
    other.x = __shfl(lgv.x, lane ^ 1);
    other.y = __shfl(lgv.y, lane ^ 1);
    other.z = __shfl(lgv.z, lane ^ 1);
    other.w = __shfl(lgv.w, lane ^ 1);
    if (lane == 0) {
      float l[8] = { lgv.x + bg[0], lgv.y + bg[1], lgv.z + bg[2], lgv.w + bg[3],
                     other.x + bg[4], other.y + bg[5], other.z + bg[6], other.w + bg[7] };
      int i0 = 0; float v0 = l[0];
      #pragma unroll
      for (int i = 1; i < 8; i++) if (l[i] > v0) { v0 = l[i]; i0 = i; }   // first max (jax tie rule)
      int i1 = -1; float v1 = -3.4e38f;
      #pragma unroll
      for (int i = 0; i < 8; i++) if (i != i0 && l[i] > v1) { v1 = l[i]; i1 = i; }
      const float e1v = __expf(v1 - v0);
      const float w0 = 1.0f / (1.0f + e1v);
      const float w1 = e1v * w0;
      float wout[8] = {0.f, 0.f, 0.f, 0.f, 0.f, 0.f, 0.f, 0.f};
      wout[i0] = w0; wout[i1] = w1;
      float4* wrow = reinterpret_cast<float4*>(outW + (size_t)t * EE);
      wrow[0] = make_float4(wout[0], wout[1], wout[2], wout[3]);
      wrow[1] = make_float4(wout[4], wout[5], wout[6], wout[7]);
      tk_e[t] = i0 | (i1 << 8);
      tk_w[2 * t] = w0; tk_w[2 * t + 1] = w1;
    }
    return;
  }
  const int tb = bid - 2048;
  const int z = tb >> 9, rem = tb & 511;
  const int bx = rem & 31, by = rem >> 5;
  const int cq = threadIdx.x & 15, rr = threadIdx.x >> 4;
  if (z < 16) {
    const int half = z >> 3, e = z & 7;
    const float* ip = (half ? W1b : W1a) + (size_t)e * DD * FF;
    const int f0 = bx * 64, d0 = by * 64;
    #pragma unroll
    for (int p = 0; p < 4; p++) {
      const int r = rr + 16 * p;
      float4 v = *reinterpret_cast<const float4*>(ip + (size_t)(d0 + r) * FF + f0 + 4 * cq);
      *reinterpret_cast<ushort4*>(&tile[r][4 * cq]) =
          make_ushort4(f2bf(v.x), f2bf(v.y), f2bf(v.z), f2bf(v.w));
    }
    __syncthreads();
    ushort* op = BT1 + (size_t)e * 4096 * DD;
    const int rq = threadIdx.x & 15, cc = threadIdx.x >> 4;
    #pragma unroll
    for (int p = 0; p < 4; p++) {
      const int f = f0 + cc + 16 * p;
      const int rmap = ((f >> 4) << 5) + half * 16 + (f & 15);
      ushort4 u = make_ushort4(tile[4 * rq + 0][cc + 16 * p], tile[4 * rq + 1][cc + 16 * p],
                               tile[4 * rq + 2][cc + 16 * p], tile[4 * rq + 3][cc + 16 * p]);
      *reinterpret_cast<ushort4*>(op + (size_t)rmap * DD + d0 + 4 * rq) = u;
    }
  } else {
    const int e = z & 7;
    const float* ip = W2 + (size_t)e * FF * DD;          // [F][D]
    const int r0 = bx * 64;                              // F dim (32 blocks)
    const int c0 = by * 64;                              // D dim (16 blocks)
    #pragma unroll
    for (int p = 0; p < 4; p++) {
      const int r = rr + 16 * p;
      float4 v = *reinterpret_cast<const float4*>(ip + (size_t)(r0 + r) * DD + c0 + 4 * cq);
      *reinterpret_cast<ushort4*>(&tile[r][4 * cq]) =
          make_ushort4(f2bf(v.x), f2bf(v.y), f2bf(v.z), f2bf(v.w));
    }
    __syncthreads();
    ushort* op = W2T + (size_t)e * DD * FF;              // [D][F]
    const int rq = threadIdx.x & 15, cc = threadIdx.x >> 4;
    #pragma unroll
    for (int p = 0; p < 4; p++) {
      const int c = cc + 16 * p;
      ushort4 u = make_ushort4(tile[4 * rq + 0][c], tile[4 * rq + 1][c],
                               tile[4 * rq + 2][c], tile[4 * rq + 3][c]);
      *reinterpret_cast<ushort4*>(op + (size_t)(c0 + c) * FF + r0 + 4 * rq) = u;
    }
  }
}

// ---------------- fused scan+scatter: 1 block per expert, no global atomics -------------------
// Writes tok_of_row (ffn1), dst_of_row = slot*NT + tok (ffn2 store target), gw_of_row.
__global__ __launch_bounds__(256) void k_scatter(
    const int* __restrict__ tk_e, const float* __restrict__ tk_w, int* __restrict__ base,
    int* __restrict__ tok_of_row, int* __restrict__ dst_of_row, float* __restrict__ gw_of_row) {
  const int e = blockIdx.x;
  const int tid = threadIdx.x, wid = tid >> 6, lane = tid & 63;
  int c[8] = {0, 0, 0, 0, 0, 0, 0, 0};
  for (int i = tid; i < NT; i += 256) {
    const int ee = tk_e[i];
    c[ee & 255]++;
    c[(ee >> 8) & 255]++;
  }
  #pragma unroll
  for (int m = 32; m; m >>= 1) {
    #pragma unroll
    for (int i = 0; i < 8; i++) c[i] += __shfl_xor(c[i], m);
  }
  __shared__ int sw[4][8];
  __shared__ int s_base[9];
  if (lane == 0) {
    #pragma unroll
    for (int i = 0; i < 8; i++) sw[wid][i] = c[i];
  }
  __syncthreads();
  if (tid == 0) {
    int acc = 0;
    for (int q = 0; q < EE; q++) {
      s_base[q] = acc;
      const int cnt = sw[0][q] + sw[1][q] + sw[2][q] + sw[3][q];
      acc += ((cnt + 127) >> 7) << 7;
    }
    s_base[EE] = acc;
  }
  __syncthreads();
  if (e == 0 && tid <= EE) base[tid] = s_base[tid];
  const int myBase = s_base[e], myEnd = s_base[e + 1];
  for (int i = myBase + tid; i < myEnd; i += 256) {
    tok_of_row[i] = -1;
    dst_of_row[i] = -1;
  }
  __syncthreads();
  __shared__ int s_cursor;
  __shared__ int s_woff[4];
  if (tid == 0) s_cursor = myBase;
  __syncthreads();
  for (int t0 = 0; t0 < NT; t0 += 256) {
    const int t = t0 + tid;
    const int ee = tk_e[t];
    const int m0 = (ee & 255) == e;
    const int m1 = ((ee >> 8) & 255) == e;
    const int has = m0 | m1;
    const unsigned long long mask = __ballot(has);
    const int prefix = __popcll(mask & ((1ull << lane) - 1ull));
    if (lane == 0) s_woff[wid] = __popcll(mask);
    __syncthreads();
    int woff = 0;
    #pragma unroll
    for (int w = 0; w < 4; w++) woff += (w < wid) ? s_woff[w] : 0;
    if (has) {
      const int row = s_cursor + woff + prefix;
      const int slot = m0 ? 0 : 1;
      tok_of_row[row] = t;
      dst_of_row[row] = slot * NT + t;
      gw_of_row[row] = tk_w[2 * t + slot];
    }
    __syncthreads();
    if (tid == 0) s_cursor += s_woff[0] + s_woff[1] + s_woff[2] + s_woff[3];
  }
}

// ---------------- grouped GEMM1 (R3/R9 structure, 128x128 tile, BK=32) — UNCHANGED ------------
__global__ __launch_bounds__(256) void k_ffn1(
    const ushort* __restrict__ xn, const ushort* __restrict__ BT1,
    const float* __restrict__ b1a, const float* __restrict__ b1b,
    const int* __restrict__ tok_of_row, const int* __restrict__ base,
    ushort* __restrict__ H) {
  const int row0 = blockIdx.y * 128;
  if (row0 >= base[EE]) return;
  int e = 0;
  while (e < EE - 1 && row0 >= base[e + 1]) e++;
  const int c0 = blockIdx.x * 128;            // interleaved column base
  const int tid = threadIdx.x, wid = tid >> 6, lane = tid & 63;
  const int wr = wid >> 1, wc = wid & 1;      // 2x2 waves, each 64x64 output
  __shared__ __align__(16) ushort smem[128 * 72];
  ushort* sA = smem;
  ushort* sB = smem + 4096;
  const int rloc = tid >> 2;                  // 0..63
  const int kcol = (((tid & 3) * 16) ^ swz_of_row(rloc)) >> 1;  // pre-swizzled src col
  int tok0 = tok_of_row[row0 + rloc];      if (tok0 < 0) tok0 = 0;
  int tok1 = tok_of_row[row0 + 64 + rloc]; if (tok1 < 0) tok1 = 0;
  const ushort* gA0 = xn + (size_t)tok0 * DD + kcol;
  const ushort* gA1 = xn + (size_t)tok1 * DD + kcol;
  const ushort* gB0 = BT1 + ((size_t)e * 4096 + c0 + rloc) * DD + kcol;
  const ushort* gB1 = BT1 + ((size_t)e * 4096 + c0 + 64 + rloc) * DD + kcol;
  ushort* lA0 = sA + wid * 512;  ushort* lA1 = sA + 2048 + wid * 512;
  ushort* lB0 = sB + wid * 512;  ushort* lB1 = sB + 2048 + wid * 512;
  const int lrow = lane & 15, q = lane >> 4;
  const int fsw = (q * 16) ^ swz_of_row(lrow);
  int aoff[4], boff[4];
  #pragma unroll
  for (int m = 0; m < 4; m++) aoff[m] = (wr * 64 + m * 16 + lrow) * 64 + fsw;
  #pragma unroll
  for (int n = 0; n < 4; n++) boff[n] = (wc * 64 + n * 16 + lrow) * 64 + fsw;
  f32x4 acc[16];
  #pragma unroll
  for (int i = 0; i < 16; i++) acc[i] = (f32x4){0.f, 0.f, 0.f, 0.f};
  for (int kt = 0; kt < DD / 32; kt++) {
    gload16(gA0 + kt * 32, lA0);
    gload16(gA1 + kt * 32, lA1);
    gload16(gB0 + kt * 32, lB0);
    gload16(gB1 + kt * 32, lB1);
    __syncthreads();
    bf16x8 fb[4];
    #pragma unroll
    for (int n = 0; n < 4; n++)
      fb[n] = *reinterpret_cast<const bf16x8*>(reinterpret_cast<const char*>(sB) + boff[n]);
    #pragma unroll
    for (int m = 0; m < 4; m++) {
      const bf16x8 fa = *reinterpret_cast<const bf16x8*>(reinterpret_cast<const char*>(sA) + aoff[m]);
      #pragma unroll
      for (int n = 0; n < 4; n++)
        acc[m * 4 + n] = __builtin_amdgcn_mfma_f32_16x16x32_bf16(fa, fb[n], acc[m * 4 + n], 0, 0, 0);
    }
    __syncthreads();
  }
  // epilogue: h = silu(a)*b into LDS, then coalesced 16B stores
  #pragma unroll
  for (int np = 0; np < 2; np++) {
    const int fl = wc * 32 + np * 16 + lrow;
    const int f = (c0 >> 1) + fl;
    const float ba_ = b1a[e * FF + f], bb_ = b1b[e * FF + f];
    #pragma unroll
    for (int m = 0; m < 4; m++) {
      #pragma unroll
      for (int r = 0; r < 4; r++) {
        const float a = acc[m * 4 + 2 * np][r] + ba_;
        const float b = acc[m * 4 + 2 * np + 1][r] + bb_;
        const float h = (a / (1.0f + __expf(-a))) * b;
        const int rl = wr * 64 + m * 16 + q * 4 + r;
        smem[rl * 72 + fl] = f2bf(h);
      }
    }
  }
  __syncthreads();
  const int fc = tid & 7, rb = tid >> 3;
  #pragma unroll
  for (int i = 0; i < 4; i++) {
    const int rl = i * 32 + rb;
    const uint4 v = *reinterpret_cast<const uint4*>(&smem[rl * 72 + fc * 8]);
    *reinterpret_cast<uint4*>(H + (size_t)(row0 + rl) * FF + (c0 >> 1) + fc * 8) = v;
  }
}

// ---------------- grouped GEMM2: Yslot[dst] = gw*(H@W2 + b2) (dense scaled stores) ------------
__global__ __launch_bounds__(256) void k_ffn2(
    const ushort* __restrict__ H, const ushort* __restrict__ W2T, const float* __restrict__ b2,
    const int* __restrict__ dst_of_row, const float* __restrict__ gw_of_row,
    const int* __restrict__ base, float* __restrict__ Yslot) {
  const int row0 = blockIdx.y * 128;
  if (row0 >= base[EE]) return;
  int e = 0;
  while (e < EE - 1 && row0 >= base[e + 1]) e++;
  const int d0 = blockIdx.x * 128;
  const int tid = threadIdx.x, wid = tid >> 6, lane = tid & 63;
  const int wr = wid >> 1, wc = wid & 1;
  __shared__ ushort sA[128 * 32], sB[128 * 32];
  const int rloc = tid >> 2;
  const int kcol = (((tid & 3) * 16) ^ swz_of_row(rloc)) >> 1;
  const ushort* gA0 = H + (size_t)(row0 + rloc) * FF + kcol;
  const ushort* gA1 = H + (size_t)(row0 + 64 + rloc) * FF + kcol;
  const ushort* gB0 = W2T + ((size_t)e * DD + d0 + rloc) * FF + kcol;
  const ushort* gB1 = W2T + ((size_t)e * DD + d0 + 64 + rloc) * FF + kcol;
  ushort* lA0 = sA + wid * 512;  ushort* lA1 = sA + 2048 + wid * 512;
  ushort* lB0 = sB + wid * 512;  ushort* lB1 = sB + 2048 + wid * 512;
  const int lrow = lane & 15, q = lane >> 4;
  const int fsw = (q * 16) ^ swz_of_row(lrow);
  int aoff[4], boff[4];
  #pragma unroll
  for (int m = 0; m < 4; m++) aoff[m] = (wr * 64 + m * 16 + lrow) * 64 + fsw;
  #pragma unroll
  for (int n = 0; n < 4; n++) boff[n] = (wc * 64 + n * 16 + lrow) * 64 + fsw;
  f32x4 acc[16];
  #pragma unroll
  for (int i = 0; i < 16; i++) acc[i] = (f32x4){0.f, 0.f, 0.f, 0.f};
  for (int kt = 0; kt < FF / 32; kt++) {
    gload16(gA0 + kt * 32, lA0);
    gload16(gA1 + kt * 32, lA1);
    gload16(gB0 + kt * 32, lB0);
    gload16(gB1 + kt * 32, lB1);
    __syncthreads();
    bf16x8 fb[4];
    #pragma unroll
    for (int n = 0; n < 4; n++)
      fb[n] = *reinterpret_cast<const bf16x8*>(reinterpret_cast<const char*>(sB) + boff[n]);
    #pragma unroll
    for (int m = 0; m < 4; m++) {
      const bf16x8 fa = *reinterpret_cast<const bf16x8*>(reinterpret_cast<const char*>(sA) + aoff[m]);
      #pragma unroll
      for (int n = 0; n < 4; n++)
        acc[m * 4 + n] = __builtin_amdgcn_mfma_f32_16x16x32_bf16(fa, fb[n], acc[m * 4 + n], 0, 0, 0);
    }
    __syncthreads();
  }
  int dcols[4]; float bias[4];
  #pragma unroll
  for (int n = 0; n < 4; n++) {
    dcols[n] = d0 + wc * 64 + n * 16 + lrow;
    bias[n] = b2[e * DD + dcols[n]];
  }
  #pragma unroll
  for (int m = 0; m < 4; m++) {
    #pragma unroll
    for (int r = 0; r < 4; r++) {
      const int grow = row0 + wr * 64 + m * 16 + q * 4 + r;
      const int dst = dst_of_row[grow];
      if (dst >= 0) {
        const float gw = gw_of_row[grow];
        float* orow = Yslot + (size_t)dst * DD;
        #pragma unroll
        for (int n = 0; n < 4; n++)
          orow[dcols[n]] = gw * (acc[m * 4 + n][r] + bias[n]);
      }
    }
  }
}

// ---------------- add: out[i] = Yslot0[i] + Yslot1[i] (pure streaming) ----------------
__global__ __launch_bounds__(256) void k_add(
    const float* __restrict__ Yslot, float* __restrict__ out0) {
  const float4* y0 = reinterpret_cast<const float4*>(Yslot);
  const float4* y1 = reinterpret_cast<const float4*>(Yslot + (size_t)NT * DD);
  float4* o = reinterpret_cast<float4*>(out0);
  const int n4 = NT * DD / 4;
  for (int i = blockIdx.x * 256 + threadIdx.x; i < n4; i += gridDim.x * 256) {
    const float4 a = y0[i], b = y1[i];
    o[i] = make_float4(a.x + b.x, a.y + b.y, a.z + b.z, a.w + b.w);
  }
}

// ---------------- workspace layout (bytes); total ~188.5 MB ----------------
// Yslot (fp32 [2*NT*DD] = 67,108,864) aliases XN+BT1 (83.9 MB, dead by ffn2 time).
#define WS_YS   ((size_t)0)
#define WS_XN   ((size_t)0)                    // bf16 [NT*DD]          16,777,216
#define WS_BT1  ((size_t)16777216)             // bf16 [EE*4096*DD]     67,108,864
#define WS_W2T  ((size_t)83886080)             // bf16 [EE*DD*FF]       33,554,432
#define WS_H    ((size_t)117440512)            // bf16 [NRCAP*FF]       70,778,880
#define WS_TOK  ((size_t)188219392)            // int  [NRCAP]          69,120
#define WS_DST  ((size_t)188288512)            // int  [NRCAP]          69,120
#define WS_GW   ((size_t)188357632)            // f32  [NRCAP]          69,120
#define WS_TKE  ((size_t)188426752)            // int  [NT]             32,768
#define WS_TKW  ((size_t)188459520)            // f32  [2*NT]           65,536
#define WS_BASE ((size_t)188525056)            // int  [9]

extern "C" void kernel_launch(void* const* d_in, const int* in_sizes, int n_in,
                              void* d_out, int out_size, void* d_ws, size_t ws_size,
                              hipStream_t stream) {
  const float* x     = (const float*)d_in[0];
  const float* rms_w = (const float*)d_in[1];
  const float* Wg    = (const float*)d_in[2];
  const float* bg    = (const float*)d_in[3];
  const float* W1a   = (const float*)d_in[4];
  const float* b1a   = (const float*)d_in[5];
  const float* W1b   = (const float*)d_in[6];
  const float* b1b   = (const float*)d_in[7];
  const float* W2    = (const float*)d_in[8];
  const float* b2    = (const float*)d_in[9];
  float* out0 = (float*)d_out;                       // [NT*DD]
  float* outW = (float*)d_out + (size_t)NT * DD;     // [NT*EE]

  char* ws = (char*)d_ws;
  ushort* xn    = (ushort*)(ws + WS_XN);
  ushort* BT1   = (ushort*)(ws + WS_BT1);
  ushort* W2T   = (ushort*)(ws + WS_W2T);
  ushort* Hbuf  = (ushort*)(ws + WS_H);
  float*  Yslot = (float*)(ws + WS_YS);
  int*    tok   = (int*)(ws + WS_TOK);
  int*    dst   = (int*)(ws + WS_DST);
  float*  gw    = (float*)(ws + WS_GW);
  int*    tk_e  = (int*)(ws + WS_TKE);
  float*  tk_w  = (float*)(ws + WS_TKW);
  int*    base  = (int*)(ws + WS_BASE);

  // front: rms_gate (2048 blocks) + all transposes (12288 blocks), one launch
  k_front<<<14336, 256, 0, stream>>>(x, rms_w, Wg, bg, W1a, W1b, W2,
                                     xn, outW, tk_e, tk_w, BT1, W2T);
  k_scatter<<<EE, 256, 0, stream>>>(tk_e, tk_w, base, tok, dst, gw);

  k_ffn1<<<dim3(4096 / 128, MAXT128), 256, 0, stream>>>(xn, BT1, b1a, b1b, tok, base, Hbuf);
  k_ffn2<<<dim3(DD / 128, MAXT128), 256, 0, stream>>>(Hbuf, W2T, b2, dst, gw, base, Yslot);
  k_add<<<2048, 256, 0, stream>>>(Yslot, out0);
}

// Round 13
// 397.643 us; speedup vs baseline: 1.0335x; 1.0335x over previous
//
#include <hip/hip_runtime.h>
#include <hip/hip_bf16.h>

// SMoE: B=4 S=2048 D=1024 F=2048 E=8 K=2
#define DD 1024
#define FF 2048
#define EE 8
#define NT 8192            // B*S tokens
#define NRCAP 17280        // 135 tiles of 128 rows
#define MAXT128 135

typedef __attribute__((ext_vector_type(8))) short bf16x8;
typedef __attribute__((ext_vector_type(4))) float f32x4;

__device__ __forceinline__ ushort f2bf(float f) {
  __hip_bfloat16 h = __float2bfloat16(f);
  return *reinterpret_cast<ushort*>(&h);
}

__device__ __forceinline__ void gload16(const void* g, void* l) {
  __builtin_amdgcn_global_load_lds((const __attribute__((address_space(1))) void*)g,
                                   (__attribute__((address_space(3))) void*)l, 16, 0, 0);
}

// 4-slot XOR swizzle for [row][32 bf16] LDS tiles (verified R1-R11: ~0 bank conflicts)
__device__ __forceinline__ int swz_of_row(int r) { return ((r >> 1) & 3) << 4; }

// ---------------- all weight transposes in ONE launch: z<8 W1a, z<16 W1b, else W2 ------------
__global__ __launch_bounds__(256) void k_transpose_all(
    const float* __restrict__ W1a, const float* __restrict__ W1b,
    const float* __restrict__ W2, ushort* __restrict__ BT1, ushort* __restrict__ W2T) {
  __shared__ ushort tile[64][68];
  const int z = blockIdx.z;
  const int cq = threadIdx.x & 15, rr = threadIdx.x >> 4;
  if (z < 16) {
    const int half = z >> 3, e = z & 7;
    const float* ip = (half ? W1b : W1a) + (size_t)e * DD * FF;
    const int f0 = blockIdx.x * 64, d0 = blockIdx.y * 64;
    #pragma unroll
    for (int p = 0; p < 4; p++) {
      const int r = rr + 16 * p;
      float4 v = *reinterpret_cast<const float4*>(ip + (size_t)(d0 + r) * FF + f0 + 4 * cq);
      *reinterpret_cast<ushort4*>(&tile[r][4 * cq]) =
          make_ushort4(f2bf(v.x), f2bf(v.y), f2bf(v.z), f2bf(v.w));
    }
    __syncthreads();
    ushort* op = BT1 + (size_t)e * 4096 * DD;
    const int rq = threadIdx.x & 15, cc = threadIdx.x >> 4;
    #pragma unroll
    for (int p = 0; p < 4; p++) {
      const int f = f0 + cc + 16 * p;
      const int rmap = ((f >> 4) << 5) + half * 16 + (f & 15);
      ushort4 u = make_ushort4(tile[4 * rq + 0][cc + 16 * p], tile[4 * rq + 1][cc + 16 * p],
                               tile[4 * rq + 2][cc + 16 * p], tile[4 * rq + 3][cc + 16 * p]);
      *reinterpret_cast<ushort4*>(op + (size_t)rmap * DD + d0 + 4 * rq) = u;
    }
  } else {
    const int e = z & 7;
    const float* ip = W2 + (size_t)e * FF * DD;          // [F][D]
    const int r0 = blockIdx.x * 64;                      // F dim (32 blocks)
    const int c0 = blockIdx.y * 64;                      // D dim (16 blocks)
    #pragma unroll
    for (int p = 0; p < 4; p++) {
      const int r = rr + 16 * p;
      float4 v = *reinterpret_cast<const float4*>(ip + (size_t)(r0 + r) * DD + c0 + 4 * cq);
      *reinterpret_cast<ushort4*>(&tile[r][4 * cq]) =
          make_ushort4(f2bf(v.x), f2bf(v.y), f2bf(v.z), f2bf(v.w));
    }
    __syncthreads();
    ushort* op = W2T + (size_t)e * DD * FF;              // [D][F]
    const int rq = threadIdx.x & 15, cc = threadIdx.x >> 4;
    #pragma unroll
    for (int p = 0; p < 4; p++) {
      const int c = cc + 16 * p;
      ushort4 u = make_ushort4(tile[4 * rq + 0][c], tile[4 * rq + 1][c],
                               tile[4 * rq + 2][c], tile[4 * rq + 3][c]);
      *reinterpret_cast<ushort4*>(op + (size_t)(c0 + c) * FF + r0 + 4 * rq) = u;
    }
  }
}

// ---------------- RMSNorm + gating: 1 wave/token; coalesced Wg reads; NO atomics --------------
__global__ __launch_bounds__(256) void k_rms_gate(
    const float* __restrict__ x, const float* __restrict__ rms_w,
    const float* __restrict__ Wg, const float* __restrict__ bg,
    ushort* __restrict__ xn, float* __restrict__ outW,
    int* __restrict__ tk_e, float* __restrict__ tk_w) {
  const int t = blockIdx.x * 4 + (threadIdx.x >> 6);
  const int lane = threadIdx.x & 63;
  const float* xrow = x + (size_t)t * DD;
  const float4* x4 = reinterpret_cast<const float4*>(xrow);
  const float4* w4 = reinterpret_cast<const float4*>(rms_w);
  const float4* Wg4 = reinterpret_cast<const float4*>(Wg);
  float4 xv[4];
  float ss = 0.f;
  #pragma unroll
  for (int i = 0; i < 4; i++) {
    xv[i] = x4[i * 64 + lane];
    ss += xv[i].x * xv[i].x + xv[i].y * xv[i].y + xv[i].z * xv[i].z + xv[i].w * xv[i].w;
  }
  #pragma unroll
  for (int m = 32; m; m >>= 1) ss += __shfl_xor(ss, m);
  const float sc = 1.0f / sqrtf(ss * (1.0f / (float)DD) + 1.1920929e-07f);  // finfo(f32).eps
  ushort4* xout = reinterpret_cast<ushort4*>(xn + (size_t)t * DD);
  #pragma unroll
  for (int i = 0; i < 4; i++) {
    const float4 wv = w4[i * 64 + lane];
    xout[i * 64 + lane] = make_ushort4(f2bf(xv[i].x * sc * wv.x), f2bf(xv[i].y * sc * wv.y),
                                       f2bf(xv[i].z * sc * wv.z), f2bf(xv[i].w * sc * wv.w));
  }
  // gating: lane l reads Wg4[l + 64k] (fully coalesced); covers expert-half (l&1) of row (l>>1)+32k
  float4 lgv = make_float4(0.f, 0.f, 0.f, 0.f);
  #pragma unroll 8
  for (int k = 0; k < 32; k++) {
    const int d = (lane >> 1) + 32 * k;
    const float s = xrow[d] * sc * rms_w[d];
    const float4 wg = Wg4[lane + 64 * k];
    lgv.x += s * wg.x; lgv.y += s * wg.y; lgv.z += s * wg.z; lgv.w += s * wg.w;
  }
  #pragma unroll
  for (int m = 32; m >= 2; m >>= 1) {
    lgv.x += __shfl_xor(lgv.x, m);
    lgv.y += __shfl_xor(lgv.y, m);
    lgv.z += __shfl_xor(lgv.z, m);
    lgv.w += __shfl_xor(lgv.w, m);
  }
  float4 other;
  other.x = __shfl(lgv.x, lane ^ 1);
  other.y = __shfl(lgv.y, lane ^ 1);
  other.z = __shfl(lgv.z, lane ^ 1);
  other.w = __shfl(lgv.w, lane ^ 1);
  if (lane == 0) {
    float l[8] = { lgv.x + bg[0], lgv.y + bg[1], lgv.z + bg[2], lgv.w + bg[3],
                   other.x + bg[4], other.y + bg[5], other.z + bg[6], other.w + bg[7] };
    int i0 = 0; float v0 = l[0];
    #pragma unroll
    for (int i = 1; i < 8; i++) if (l[i] > v0) { v0 = l[i]; i0 = i; }   // first max (jax tie rule)
    int i1 = -1; float v1 = -3.4e38f;
    #pragma unroll
    for (int i = 0; i < 8; i++) if (i != i0 && l[i] > v1) { v1 = l[i]; i1 = i; }
    const float e1v = __expf(v1 - v0);
    const float w0 = 1.0f / (1.0f + e1v);
    const float w1 = e1v * w0;
    float wout[8] = {0.f, 0.f, 0.f, 0.f, 0.f, 0.f, 0.f, 0.f};
    wout[i0] = w0; wout[i1] = w1;
    float4* wrow = reinterpret_cast<float4*>(outW + (size_t)t * EE);
    wrow[0] = make_float4(wout[0], wout[1], wout[2], wout[3]);
    wrow[1] = make_float4(wout[4], wout[5], wout[6], wout[7]);
    tk_e[t] = i0 | (i1 << 8);
    tk_w[2 * t] = w0; tk_w[2 * t + 1] = w1;
  }
}

// ---------------- fused scan+scatter: 1 block per expert, no global atomics -------------------
// Each block histograms tk_e, derives all bases locally, inits its own segment, then
// order-preserving ballot-prefix scatter. Records tok_of_row AND rows_of_tok (for gather).
__global__ __launch_bounds__(256) void k_scatter(
    const int* __restrict__ tk_e, int* __restrict__ base,
    int* __restrict__ tok_of_row, int* __restrict__ rows_of_tok) {
  const int e = blockIdx.x;
  const int tid = threadIdx.x, wid = tid >> 6, lane = tid & 63;
  int c[8] = {0, 0, 0, 0, 0, 0, 0, 0};
  for (int i = tid; i < NT; i += 256) {
    const int ee = tk_e[i];
    c[ee & 255]++;
    c[(ee >> 8) & 255]++;
  }
  #pragma unroll
  for (int m = 32; m; m >>= 1) {
    #pragma unroll
    for (int i = 0; i < 8; i++) c[i] += __shfl_xor(c[i], m);
  }
  __shared__ int sw[4][8];
  __shared__ int s_base[9];
  if (lane == 0) {
    #pragma unroll
    for (int i = 0; i < 8; i++) sw[wid][i] = c[i];
  }
  __syncthreads();
  if (tid == 0) {
    int acc = 0;
    for (int q = 0; q < EE; q++) {
      s_base[q] = acc;
      const int cnt = sw[0][q] + sw[1][q] + sw[2][q] + sw[3][q];
      acc += ((cnt + 127) >> 7) << 7;
    }
    s_base[EE] = acc;
  }
  __syncthreads();
  if (e == 0 && tid <= EE) base[tid] = s_base[tid];
  const int myBase = s_base[e], myEnd = s_base[e + 1];
  for (int i = myBase + tid; i < myEnd; i += 256) tok_of_row[i] = -1;
  __syncthreads();
  __shared__ int s_cursor;
  __shared__ int s_woff[4];
  if (tid == 0) s_cursor = myBase;
  __syncthreads();
  for (int t0 = 0; t0 < NT; t0 += 256) {
    const int t = t0 + tid;
    const int ee = tk_e[t];
    const int m0 = (ee & 255) == e;
    const int m1 = ((ee >> 8) & 255) == e;
    const int has = m0 | m1;
    const unsigned long long mask = __ballot(has);
    const int prefix = __popcll(mask & ((1ull << lane) - 1ull));
    if (lane == 0) s_woff[wid] = __popcll(mask);
    __syncthreads();
    int woff = 0;
    #pragma unroll
    for (int w = 0; w < 4; w++) woff += (w < wid) ? s_woff[w] : 0;
    if (has) {
      const int row = s_cursor + woff + prefix;
      tok_of_row[row] = t;
      rows_of_tok[2 * t + (m0 ? 0 : 1)] = row;
    }
    __syncthreads();
    if (tid == 0) s_cursor += s_woff[0] + s_woff[1] + s_woff[2] + s_woff[3];
  }
}

// ---------------- grouped GEMM1 (R3/R9 structure, 128x128 tile, BK=32) — UNCHANGED ------------
__global__ __launch_bounds__(256) void k_ffn1(
    const ushort* __restrict__ xn, const ushort* __restrict__ BT1,
    const float* __restrict__ b1a, const float* __restrict__ b1b,
    const int* __restrict__ tok_of_row, const int* __restrict__ base,
    ushort* __restrict__ H) {
  const int row0 = blockIdx.y * 128;
  if (row0 >= base[EE]) return;
  int e = 0;
  while (e < EE - 1 && row0 >= base[e + 1]) e++;
  const int c0 = blockIdx.x * 128;            // interleaved column base
  const int tid = threadIdx.x, wid = tid >> 6, lane = tid & 63;
  const int wr = wid >> 1, wc = wid & 1;      // 2x2 waves, each 64x64 output
  __shared__ __align__(16) ushort smem[128 * 72];
  ushort* sA = smem;
  ushort* sB = smem + 4096;
  const int rloc = tid >> 2;                  // 0..63
  const int kcol = (((tid & 3) * 16) ^ swz_of_row(rloc)) >> 1;  // pre-swizzled src col
  int tok0 = tok_of_row[row0 + rloc];      if (tok0 < 0) tok0 = 0;
  int tok1 = tok_of_row[row0 + 64 + rloc]; if (tok1 < 0) tok1 = 0;
  const ushort* gA0 = xn + (size_t)tok0 * DD + kcol;
  const ushort* gA1 = xn + (size_t)tok1 * DD + kcol;
  const ushort* gB0 = BT1 + ((size_t)e * 4096 + c0 + rloc) * DD + kcol;
  const ushort* gB1 = BT1 + ((size_t)e * 4096 + c0 + 64 + rloc) * DD + kcol;
  ushort* lA0 = sA + wid * 512;  ushort* lA1 = sA + 2048 + wid * 512;
  ushort* lB0 = sB + wid * 512;  ushort* lB1 = sB + 2048 + wid * 512;
  const int lrow = lane & 15, q = lane >> 4;
  const int fsw = (q * 16) ^ swz_of_row(lrow);
  int aoff[4], boff[4];
  #pragma unroll
  for (int m = 0; m < 4; m++) aoff[m] = (wr * 64 + m * 16 + lrow) * 64 + fsw;
  #pragma unroll
  for (int n = 0; n < 4; n++) boff[n] = (wc * 64 + n * 16 + lrow) * 64 + fsw;
  f32x4 acc[16];
  #pragma unroll
  for (int i = 0; i < 16; i++) acc[i] = (f32x4){0.f, 0.f, 0.f, 0.f};
  for (int kt = 0; kt < DD / 32; kt++) {
    gload16(gA0 + kt * 32, lA0);
    gload16(gA1 + kt * 32, lA1);
    gload16(gB0 + kt * 32, lB0);
    gload16(gB1 + kt * 32, lB1);
    __syncthreads();
    bf16x8 fb[4];
    #pragma unroll
    for (int n = 0; n < 4; n++)
      fb[n] = *reinterpret_cast<const bf16x8*>(reinterpret_cast<const char*>(sB) + boff[n]);
    #pragma unroll
    for (int m = 0; m < 4; m++) {
      const bf16x8 fa = *reinterpret_cast<const bf16x8*>(reinterpret_cast<const char*>(sA) + aoff[m]);
      #pragma unroll
      for (int n = 0; n < 4; n++)
        acc[m * 4 + n] = __builtin_amdgcn_mfma_f32_16x16x32_bf16(fa, fb[n], acc[m * 4 + n], 0, 0, 0);
    }
    __syncthreads();
  }
  // epilogue: h = silu(a)*b into LDS, then coalesced 16B stores
  #pragma unroll
  for (int np = 0; np < 2; np++) {
    const int fl = wc * 32 + np * 16 + lrow;
    const int f = (c0 >> 1) + fl;
    const float ba_ = b1a[e * FF + f], bb_ = b1b[e * FF + f];
    #pragma unroll
    for (int m = 0; m < 4; m++) {
      #pragma unroll
      for (int r = 0; r < 4; r++) {
        const float a = acc[m * 4 + 2 * np][r] + ba_;
        const float b = acc[m * 4 + 2 * np + 1][r] + bb_;
        const float h = (a / (1.0f + __expf(-a))) * b;
        const int rl = wr * 64 + m * 16 + q * 4 + r;
        smem[rl * 72 + fl] = f2bf(h);
      }
    }
  }
  __syncthreads();
  const int fc = tid & 7, rb = tid >> 3;
  #pragma unroll
  for (int i = 0; i < 4; i++) {
    const int rl = i * 32 + rb;
    const uint4 v = *reinterpret_cast<const uint4*>(&smem[rl * 72 + fc * 8]);
    *reinterpret_cast<uint4*>(H + (size_t)(row0 + rl) * FF + (c0 >> 1) + fc * 8) = v;
  }
}

// ---------------- grouped GEMM2 (R9 structure): Y[row] = H@W2 + b2 (dense stores) -------------
__global__ __launch_bounds__(256) void k_ffn2(
    const ushort* __restrict__ H, const ushort* __restrict__ W2T, const float* __restrict__ b2,
    const int* __restrict__ base, float* __restrict__ Y) {
  const int row0 = blockIdx.y * 128;
  if (row0 >= base[EE]) return;
  int e = 0;
  while (e < EE - 1 && row0 >= base[e + 1]) e++;
  const int d0 = blockIdx.x * 128;
  const int tid = threadIdx.x, wid = tid >> 6, lane = tid & 63;
  const int wr = wid >> 1, wc = wid & 1;
  __shared__ ushort sA[128 * 32], sB[128 * 32];
  const int rloc = tid >> 2;
  const int kcol = (((tid & 3) * 16) ^ swz_of_row(rloc)) >> 1;
  const ushort* gA0 = H + (size_t)(row0 + rloc) * FF + kcol;
  const ushort* gA1 = H + (size_t)(row0 + 64 + rloc) * FF + kcol;
  const ushort* gB0 = W2T + ((size_t)e * DD + d0 + rloc) * FF + kcol;
  const ushort* gB1 = W2T + ((size_t)e * DD + d0 + 64 + rloc) * FF + kcol;
  ushort* lA0 = sA + wid * 512;  ushort* lA1 = sA + 2048 + wid * 512;
  ushort* lB0 = sB + wid * 512;  ushort* lB1 = sB + 2048 + wid * 512;
  const int lrow = lane & 15, q = lane >> 4;
  const int fsw = (q * 16) ^ swz_of_row(lrow);
  int aoff[4], boff[4];
  #pragma unroll
  for (int m = 0; m < 4; m++) aoff[m] = (wr * 64 + m * 16 + lrow) * 64 + fsw;
  #pragma unroll
  for (int n = 0; n < 4; n++) boff[n] = (wc * 64 + n * 16 + lrow) * 64 + fsw;
  f32x4 acc[16];
  #pragma unroll
  for (int i = 0; i < 16; i++) acc[i] = (f32x4){0.f, 0.f, 0.f, 0.f};
  for (int kt = 0; kt < FF / 32; kt++) {
    gload16(gA0 + kt * 32, lA0);
    gload16(gA1 + kt * 32, lA1);
    gload16(gB0 + kt * 32, lB0);
    gload16(gB1 + kt * 32, lB1);
    __syncthreads();
    bf16x8 fb[4];
    #pragma unroll
    for (int n = 0; n < 4; n++)
      fb[n] = *reinterpret_cast<const bf16x8*>(reinterpret_cast<const char*>(sB) + boff[n]);
    #pragma unroll
    for (int m = 0; m < 4; m++) {
      const bf16x8 fa = *reinterpret_cast<const bf16x8*>(reinterpret_cast<const char*>(sA) + aoff[m]);
      #pragma unroll
      for (int n = 0; n < 4; n++)
        acc[m * 4 + n] = __builtin_amdgcn_mfma_f32_16x16x32_bf16(fa, fb[n], acc[m * 4 + n], 0, 0, 0);
    }
    __syncthreads();
  }
  #pragma unroll
  for (int n = 0; n < 4; n++) {
    const int dcol = d0 + wc * 64 + n * 16 + lrow;
    const float bias = b2[e * DD + dcol];
    #pragma unroll
    for (int m = 0; m < 4; m++) {
      #pragma unroll
      for (int r = 0; r < 4; r++) {
        const int grow = row0 + wr * 64 + m * 16 + q * 4 + r;
        Y[(size_t)grow * DD + dcol] = acc[m * 4 + n][r] + bias;
      }
    }
  }
}

// ---------------- gather (grid-stride): out[t] = w0*Y[r0] + w1*Y[r1] ----------------
__global__ __launch_bounds__(256) void k_gather(
    const float* __restrict__ Y, const int* __restrict__ rows_of_tok,
    const float* __restrict__ tk_w, float* __restrict__ out0) {
  for (int t = blockIdx.x; t < NT; t += gridDim.x) {
    const int r0 = rows_of_tok[2 * t], r1 = rows_of_tok[2 * t + 1];
    const float w0 = tk_w[2 * t], w1 = tk_w[2 * t + 1];
    const float4 y0 = reinterpret_cast<const float4*>(Y + (size_t)r0 * DD)[threadIdx.x];
    const float4 y1 = reinterpret_cast<const float4*>(Y + (size_t)r1 * DD)[threadIdx.x];
    float4 o;
    o.x = w0 * y0.x + w1 * y1.x;
    o.y = w0 * y0.y + w1 * y1.y;
    o.z = w0 * y0.z + w1 * y1.z;
    o.w = w0 * y0.w + w1 * y1.w;
    reinterpret_cast<float4*>(out0 + (size_t)t * DD)[threadIdx.x] = o;
  }
}

// ---------------- workspace layout (bytes); total ~188.5 MB ----------------
// Y (fp32 [NRCAP*DD] = 70,778,880) aliases XN+BT1 (83.9 MB, dead by ffn2 time).
#define WS_Y    ((size_t)0)
#define WS_XN   ((size_t)0)                    // bf16 [NT*DD]          16,777,216
#define WS_BT1  ((size_t)16777216)             // bf16 [EE*4096*DD]     67,108,864
#define WS_W2T  ((size_t)83886080)             // bf16 [EE*DD*FF]       33,554,432
#define WS_H    ((size_t)117440512)            // bf16 [NRCAP*FF]       70,778,880
#define WS_TOK  ((size_t)188219392)            // int  [NRCAP]          69,120
#define WS_ROWS ((size_t)188288512)            // int  [2*NT]           65,536
#define WS_TKE  ((size_t)188354048)            // int  [NT]             32,768
#define WS_TKW  ((size_t)188386816)            // f32  [2*NT]           65,536
#define WS_BASE ((size_t)188452352)            // int  [9]

extern "C" void kernel_launch(void* const* d_in, const int* in_sizes, int n_in,
                              void* d_out, int out_size, void* d_ws, size_t ws_size,
                              hipStream_t stream) {
  const float* x     = (const float*)d_in[0];
  const float* rms_w = (const float*)d_in[1];
  const float* Wg    = (const float*)d_in[2];
  const float* bg    = (const float*)d_in[3];
  const float* W1a   = (const float*)d_in[4];
  const float* b1a   = (const float*)d_in[5];
  const float* W1b   = (const float*)d_in[6];
  const float* b1b   = (const float*)d_in[7];
  const float* W2    = (const float*)d_in[8];
  const float* b2    = (const float*)d_in[9];
  float* out0 = (float*)d_out;                       // [NT*DD]
  float* outW = (float*)d_out + (size_t)NT * DD;     // [NT*EE]

  char* ws = (char*)d_ws;
  ushort* xn    = (ushort*)(ws + WS_XN);
  ushort* BT1   = (ushort*)(ws + WS_BT1);
  ushort* W2T   = (ushort*)(ws + WS_W2T);
  ushort* Hbuf  = (ushort*)(ws + WS_H);
  float*  Ybuf  = (float*)(ws + WS_Y);
  int*    tok   = (int*)(ws + WS_TOK);
  int*    rows  = (int*)(ws + WS_ROWS);
  int*    tk_e  = (int*)(ws + WS_TKE);
  float*  tk_w  = (float*)(ws + WS_TKW);
  int*    base  = (int*)(ws + WS_BASE);

  // all weight transposes, one launch
  k_transpose_all<<<dim3(32, 16, 24), 256, 0, stream>>>(W1a, W1b, W2, BT1, W2T);

  k_rms_gate<<<NT / 4, 256, 0, stream>>>(x, rms_w, Wg, bg, xn, outW, tk_e, tk_w);
  k_scatter<<<EE, 256, 0, stream>>>(tk_e, base, tok, rows);

  k_ffn1<<<dim3(4096 / 128, MAXT128), 256, 0, stream>>>(xn, BT1, b1a, b1b, tok, base, Hbuf);
  k_ffn2<<<dim3(DD / 128, MAXT128), 256, 0, stream>>>(Hbuf, W2T, b2, base, Ybuf);
  k_gather<<<2048, 256, 0, stream>>>(Ybuf, rows, tk_w, out0);
}